// Round 6
// baseline (2731.044 us; speedup 1.0000x reference)
//
#include <hip/hip_runtime.h>
#include <hip/hip_bf16.h>

typedef __attribute__((ext_vector_type(8))) short short8;
typedef __attribute__((ext_vector_type(4))) float f32x4;
typedef unsigned long long u64;
typedef unsigned int u32;

#define SQLEN 256
#define BATCH 128
#define HID   1024
#define NCLS  1000

static __device__ __forceinline__ float sigm(float x){ return 1.0f/(1.0f+__expf(-x)); }
static __device__ __forceinline__ float tanhx(float x){ return 2.0f/(1.0f+__expf(-2.0f*x)) - 1.0f; }
static __device__ __forceinline__ short bf16b(float x){
  __hip_bfloat16 h = __float2bfloat16(x);
  return __builtin_bit_cast(short, h);
}
static __device__ __forceinline__ float bf2f(short s){
  return __bfloat162float(__builtin_bit_cast(__hip_bfloat16, s));
}

// ---- prep: cast x [B][S][I] fp32 -> xbf [(s*128+b)][I] bf16 (permuted) ----
__global__ void cast_x_kernel(const float* __restrict__ x, short* __restrict__ xbf){
  int r = blockIdx.x;            // r = s*128 + b
  int s = r >> 7, b = r & 127;
  const float* src = x + ((size_t)b*SQLEN + s)*HID;
  short* dst = xbf + (size_t)r*HID;
  int k = threadIdx.x*4;
  float4 v = *(const float4*)(src + k);
  short4 o; o.x=bf16b(v.x); o.y=bf16b(v.y); o.z=bf16b(v.z); o.w=bf16b(v.w);
  *(short4*)(dst + k) = o;
}

__global__ void cast_w_kernel(const float* __restrict__ src, short* __restrict__ dst){
  int i = (blockIdx.x*256 + threadIdx.x)*4;
  float4 v = *(const float4*)(src + i);
  short4 o; o.x=bf16b(v.x); o.y=bf16b(v.y); o.z=bf16b(v.z); o.w=bf16b(v.w);
  *(short4*)(dst + i) = o;
}

__global__ void bias_kernel(const float* __restrict__ a, const float* __restrict__ b,
                            float* __restrict__ o){
  int i = blockIdx.x*256 + threadIdx.x;
  o[i] = a[i] + b[i];
}

// ---- fused xw-GEMM + persistent LSTM recurrence ----
// Recurrence = byte-exact R1 structure (962us lstm; every modification to it
// regressed: pin +1365us, per-wave protocol +418us). The xw GEMM (275 GFLOP,
// previously a ~500-650us standalone kernel) is folded into the recurrence's
// idle capacity (MfmaUtil was 8%): each block owns 16 gemm tiles
// (t_id = k*512 + blockIdx, so tile round k covers s=16k..16k+15 chip-wide).
//  * prologue: tile 0 full (s=0..15 ready before step 0)
//  * steps 0..119: 4 gemm K-steps per recurrence step, placed between the
//    h-store and the tail barrier (which drained vmcnt anyway). Tile k done
//    at step 8k-1; s=16k first needed ~step 16k -> margin >= 8k steps.
//  * xw writes: agent-scope stores (same proven mechanism as h); per-s
//    counter gcnt[s] incremented after a draining barrier; the xw prefetch
//    is gated by a one-load poll of gcnt (never spins under the schedule;
//    guards correctness against inter-bg drift).
// Deadlock audit: gemm chunks are local work only; h-flag graph acyclic in
// t (unchanged from R1); gcnt only increases and producers never wait on
// consumers ahead of them. LDS 48KB, 2 blocks/CU preserved.
__global__ __launch_bounds__(256,2) void lstm_fused_kernel(
    const short* __restrict__ xbf, const short* __restrict__ wxh,
    const float* __restrict__ bias, const short* __restrict__ whh,
    short* __restrict__ xw, short* __restrict__ h_all,
    u32* __restrict__ flags, u32* __restrict__ gcnt)
{
  __shared__ f32x4 part[2][4][4][64];            // 32 KB reduce buffer
  __shared__ __align__(16) short As[4096];       // 8 KB gemm A stage [128][32]
  __shared__ __align__(16) short Bs[4096];       // 8 KB gemm B stage

  const int tid  = threadIdx.x;
  const int lane = tid & 63;
  const int wave = tid >> 6;            // recurrence K-slice 0..3 (256 each)
  const int l15  = lane & 15;
  const int quad = lane >> 4;
  const int bg = blockIdx.x & 7;        // batch group
  const int jg = blockIdx.x >> 3;       // 0..63
  const int b0 = bg*16;
  const int j0 = jg*16;
  const int ks0 = wave*256;
  const int wm = (wave>>1)*64, wn = (wave&1)*64; // gemm output quadrant
  const int c0 = wave*64 + lane;        // gemm staging slot, rep 0
  const int c1 = c0 + 256;              // rep 1

  __builtin_amdgcn_fence(__ATOMIC_ACQUIRE, "agent");  // once: clear stale L2

  f32x4 gacc[4][4];
  auto gzero = [&]{
    #pragma unroll
    for (int m=0;m<4;++m)
      #pragma unroll
      for (int n=0;n<4;++n) gacc[m][n] = (f32x4)0.0f;
  };
  // one gemm K-step (BK=32) of the current tile
  auto gemm_kk = [&](size_t gr0, size_t gn0, int kk){
    const int k0 = kk*32;
    __syncthreads();   // previous kk's LDS reads done
    __builtin_amdgcn_global_load_lds(
        (const void*)(xbf + (gr0 + (c0>>2))*HID + k0 + (c0&3)*8),
        (void*)((char*)As + wave*1024), 16, 0, 0);
    __builtin_amdgcn_global_load_lds(
        (const void*)(xbf + (gr0 + (c1>>2))*HID + k0 + (c1&3)*8),
        (void*)((char*)As + 4096 + wave*1024), 16, 0, 0);
    __builtin_amdgcn_global_load_lds(
        (const void*)(wxh + (gn0 + (c0>>2))*HID + k0 + (c0&3)*8),
        (void*)((char*)Bs + wave*1024), 16, 0, 0);
    __builtin_amdgcn_global_load_lds(
        (const void*)(wxh + (gn0 + (c1>>2))*HID + k0 + (c1&3)*8),
        (void*)((char*)Bs + 4096 + wave*1024), 16, 0, 0);
    __syncthreads();   // DMA landed (barrier drains vmcnt)
    short8 af[4], bv[4];
    #pragma unroll
    for (int m=0;m<4;++m) af[m] = *(const short8*)(As + (wm + m*16 + l15)*32 + quad*8);
    #pragma unroll
    for (int n=0;n<4;++n) bv[n] = *(const short8*)(Bs + (wn + n*16 + l15)*32 + quad*8);
    #pragma unroll
    for (int m=0;m<4;++m)
      #pragma unroll
      for (int n=0;n<4;++n)
        gacc[m][n] = __builtin_amdgcn_mfma_f32_16x16x32_bf16(af[m], bv[n], gacc[m][n], 0,0,0);
  };
  // tile epilogue: bias + pack -> agent-scope 8B stores, then count
  auto gemm_epi = [&](int gbm, int gbn){
    #pragma unroll
    for (int n=0;n<4;++n){
      int s = gbn*128 + wn + n*16;
      float bs = bias[s + l15];
      int g = s >> 10, jgi = (s & 1023) >> 4;
      #pragma unroll
      for (int m=0;m<4;++m){
        #pragma unroll
        for (int rg=0; rg<4; ++rg){
          u32 w0 = (u32)(unsigned short)bf16b(gacc[m][n][rg] + bs);
          u32 w1 = __shfl_down(w0, 1);
          u32 w2 = __shfl_down(w0, 2);
          u32 w3 = __shfl_down(w0, 3);
          if ((l15 & 3) == 0){
            u64 pk = (u64)w0 | ((u64)w1<<16) | ((u64)w2<<32) | ((u64)w3<<48);
            int rowin = wm + m*16 + quad*4 + rg;   // batch b 0..127
            __hip_atomic_store(
              (u64*)(xw + (((size_t)gbm*64 + jgi)*128 + rowin)*64 + g*16 + l15),
              pk, __ATOMIC_RELAXED, __HIP_MEMORY_SCOPE_AGENT);
          }
        }
      }
    }
    __syncthreads();   // all waves' xw stores drained (vmcnt0 at barrier)
    if (tid == 0)
      __hip_atomic_fetch_add(gcnt + gbm, 1u, __ATOMIC_RELAXED,
                             __HIP_MEMORY_SCOPE_AGENT);
  };

  // ---- gemm prologue: tile 0 (chip-wide this covers s=0..15) ----
  gzero();
  {
    const int t_id = (int)blockIdx.x;
    const int gbm = t_id >> 5, gbn = t_id & 31;
    const size_t gr0 = (size_t)gbm*128, gn0 = (size_t)gbn*128;
    for (int kk = 0; kk < 32; ++kk) gemm_kk(gr0, gn0, kk);
    gemm_epi(gbm, gbn);
    gzero();
  }

  // Whh slice, MFMA B-fragment layout (no pinning -- see rounds 2/3)
  short8 Bf[4][8];
  #pragma unroll
  for (int g=0; g<4; ++g)
    #pragma unroll
    for (int kit=0; kit<8; ++kit)
      Bf[g][kit] = *(const short8*)(whh + (size_t)(g*1024 + j0 + l15)*HID
                                    + ks0 + kit*32 + quad*8);

  u32* fgrp = flags + bg*64;            // one h-flag per producer block

  // elementwise cell mapping: cell = tid (r 0..15 x jj 0..15)
  const int r  = tid >> 4;
  const int jj = tid & 15;
  const int ln = (r>>2)*16 + jj;        // frag lane of cell
  const int rg = r & 3;                 // frag reg of cell
  float cc = 0.0f;                      // cell state in register

  // gated prefetch of xw for t=0
  short xwc[4];
  {
    while (__hip_atomic_load(gcnt + 0, __ATOMIC_RELAXED,
                             __HIP_MEMORY_SCOPE_AGENT) < 32u)
      __builtin_amdgcn_s_sleep(1);
    asm volatile("" ::: "memory");
    const short* xb = xw + (((size_t)0*64 + jg)*128 + b0 + r)*64 + jj;
    #pragma unroll
    for (int g=0; g<4; ++g) xwc[g] = xb[g*16];
  }

  for (int t = 0; t < SQLEN; ++t){
    const short* hin  = h_all + (size_t)t*131072;
    short*       hout = h_all + (size_t)(t+1)*131072;

    // gated early prefetch of next step's xw (poll is one L2 load when
    // satisfied -- by schedule s=t+1 is ready >= 8k steps early)
    short xwn[4];
    if (t < SQLEN-1){
      while (__hip_atomic_load(gcnt + (t+1), __ATOMIC_RELAXED,
                               __HIP_MEMORY_SCOPE_AGENT) < 32u)
        __builtin_amdgcn_s_sleep(1);
      asm volatile("" ::: "memory");
      const short* xb = xw + (((size_t)(t+1)*64 + jg)*128 + b0 + r)*64 + jj;
      #pragma unroll
      for (int g=0; g<4; ++g) xwn[g] = xb[g*16];
    }

    // per-wave spin: the 16 producer blocks of THIS wave's K-slice
    if (t){
      u32* fp = fgrp + wave*16 + l15;
      while (__hip_atomic_load(fp, __ATOMIC_RELAXED,
                               __HIP_MEMORY_SCOPE_AGENT) < (u32)t)
        __builtin_amdgcn_s_sleep(1);
      asm volatile("" ::: "memory");    // no hoist of h loads above the spin
    }

    // h fragments: plain cached coalesced 16B loads (fresh addresses)
    short8 Af[8];
    #pragma unroll
    for (int kit=0; kit<8; ++kit)
      Af[kit] = *(const short8*)(hin + (size_t)(b0 + l15)*HID
                                 + ks0 + kit*32 + quad*8);

    f32x4 acc[4];
    #pragma unroll
    for (int g=0; g<4; ++g) acc[g] = (f32x4)0.0f;
    #pragma unroll
    for (int kit=0; kit<8; ++kit)
      #pragma unroll
      for (int g=0; g<4; ++g)
        acc[g] = __builtin_amdgcn_mfma_f32_16x16x32_bf16(Af[kit], Bf[g][kit], acc[g],0,0,0);

    // single-pass cross-wave reduce, all 4 gates, double-buffered
    const int pb = t & 1;
    #pragma unroll
    for (int g=0; g<4; ++g) part[pb][wave][g][lane] = acc[g];
    __syncthreads();

    float gv[4];
    #pragma unroll
    for (int g=0; g<4; ++g){
      float s = bf2f(xwc[g]);
      #pragma unroll
      for (int w=0; w<4; ++w)
        s += ((const float*)&part[pb][w][g][ln])[rg];
      gv[g] = s;
    }

    float it = sigm(gv[0]), ft = sigm(gv[1]), ch = tanhx(gv[2]), ot = sigm(gv[3]);
    cc = cc*ft + it*ch;
    float hv = ot * tanhx(cc);

    // pack 4 adjacent cells -> one 8B write-through store
    u32 w0 = (u32)(unsigned short)bf16b(hv);
    u32 w1 = __shfl_down(w0, 1);
    u32 w2 = __shfl_down(w0, 2);
    u32 w3 = __shfl_down(w0, 3);
    if (!(tid & 3)){
      u64 hp = (u64)w0 | ((u64)w1<<16) | ((u64)w2<<32) | ((u64)w3<<48);
      __hip_atomic_store((u64*)(hout + (size_t)(b0 + r)*HID + j0 + jj), hp,
                         __ATOMIC_RELAXED, __HIP_MEMORY_SCOPE_AGENT);
    }
    xwc[0]=xwn[0]; xwc[1]=xwn[1]; xwc[2]=xwn[2]; xwc[3]=xwn[3];

    // gemm chunk: 4 K-steps of tile k = 1+(t>>3); tiles 1..15 over steps
    // 0..119, each tile spanning 8 steps. Sits where the tail barrier
    // already paid a vmcnt drain.
    if (t < 120){
      const int k = 1 + (t>>3);
      const int t_id = k*512 + (int)blockIdx.x;
      const int gbm = t_id >> 5, gbn = t_id & 31;
      const size_t gr0 = (size_t)gbm*128, gn0 = (size_t)gbn*128;
      const int kkb = (t&7)*4;
      #pragma unroll
      for (int q=0; q<4; ++q) gemm_kk(gr0, gn0, kkb+q);
      if ((t&7)==7){ gemm_epi(gbm, gbn); gzero(); }
    }

    __syncthreads();   // all waves' h stores drained (vmcnt0 at barrier)

    if (t < SQLEN-1 && tid == 0)
      __hip_atomic_store(fgrp + jg, (u32)(t+1), __ATOMIC_RELAXED,
                         __HIP_MEMORY_SCOPE_AGENT);   // plain store, no RMW
  }
}

// ---- phase 3: out[b][c] = h[b]. Wfc[c] + bfc[c], fp32 ----
__global__ __launch_bounds__(256) void fc_kernel(const short* __restrict__ h,
    const float* __restrict__ wfc, const float* __restrict__ bfc, float* __restrict__ out)
{
  __shared__ float hs[4][1024];
  int tid = threadIdx.x;
  int b0 = blockIdx.x*4;
  for (int i = tid; i < 4096; i += 256){
    int bb = i >> 10, k = i & 1023;
    hs[bb][k] = bf2f(h[(size_t)(b0+bb)*HID + k]);
  }
  __syncthreads();
  for (int c = tid; c < NCLS; c += 256){
    const float* w = wfc + (size_t)c*HID;
    float a0=0.f,a1=0.f,a2=0.f,a3=0.f;
    for (int k=0; k<1024; k+=4){
      float4 wv = *(const float4*)(w + k);
      a0 += wv.x*hs[0][k] + wv.y*hs[0][k+1] + wv.z*hs[0][k+2] + wv.w*hs[0][k+3];
      a1 += wv.x*hs[1][k] + wv.y*hs[1][k+1] + wv.z*hs[1][k+2] + wv.w*hs[1][k+3];
      a2 += wv.x*hs[2][k] + wv.y*hs[2][k+1] + wv.z*hs[2][k+2] + wv.w*hs[2][k+3];
      a3 += wv.x*hs[3][k] + wv.y*hs[3][k+1] + wv.z*hs[3][k+2] + wv.w*hs[3][k+3];
    }
    float bb = bfc[c];
    out[(size_t)(b0+0)*NCLS + c] = a0 + bb;
    out[(size_t)(b0+1)*NCLS + c] = a1 + bb;
    out[(size_t)(b0+2)*NCLS + c] = a2 + bb;
    out[(size_t)(b0+3)*NCLS + c] = a3 + bb;
  }
}

extern "C" void kernel_launch(void* const* d_in, const int* in_sizes, int n_in,
                              void* d_out, int out_size, void* d_ws, size_t ws_size,
                              hipStream_t stream) {
  const float* x   = (const float*)d_in[0];
  const float* Wxh = (const float*)d_in[1];
  const float* bxh = (const float*)d_in[2];
  const float* Whh = (const float*)d_in[3];
  const float* bhh = (const float*)d_in[4];
  const float* Wfc = (const float*)d_in[5];
  const float* bfc = (const float*)d_in[6];
  float* out = (float*)d_out;

  char* ws = (char*)d_ws;
  // xbf stays LIVE through the fused kernel (gemm A source) -> h_all no
  // longer aliases it; workspace high-water ~422 MB.
  short*    xbf   = (short*)(ws + 0);            // 64 MB
  short*    wxhb  = (short*)(ws + 68157440);     // 65 MB
  short*    whhb  = (short*)(ws + 76546048);     // 73 MB
  float*    biasg = (float*)(ws + 84934656);     // 81 MB
  short*    xw    = (short*)(ws + 85983232);     // 82 MB, 256 MB gate-blocked
  short*    h_all = (short*)(ws + 354418688);    // 338 MB, 257 x 256 KB
  u32*      flags = (u32*)(ws + 421789696);      // 512 h-flags
  u32*      gcnt  = (u32*)(ws + 421793792);      // 256 per-s gemm counters

  hipMemsetAsync(flags, 0, 8192, stream);        // covers flags + gcnt

  cast_x_kernel<<<32768, 256, 0, stream>>>(x, xbf);
  cast_w_kernel<<<4096, 256, 0, stream>>>(Wxh, wxhb);
  cast_w_kernel<<<4096, 256, 0, stream>>>(Whh, whhb);
  bias_kernel  <<<16,   256, 0, stream>>>(bxh, bhh, biasg);
  hipMemsetAsync(h_all, 0, 262144, stream);      // h_all[0] = 0
  lstm_fused_kernel<<<512, 256, 0, stream>>>(xbf, wxhb, biasg, whhb,
                                             xw, h_all, flags, gcnt);
  fc_kernel    <<<32,   256, 0, stream>>>(h_all + (size_t)SQLEN*131072, Wfc, bfc, out);
}

// Round 7
// 2667.233 us; speedup vs baseline: 1.0239x; 1.0239x over previous
//
#include <hip/hip_runtime.h>
#include <hip/hip_bf16.h>

typedef __attribute__((ext_vector_type(8))) short short8;
typedef __attribute__((ext_vector_type(4))) float f32x4;
typedef unsigned long long u64;
typedef unsigned int u32;

#define SQLEN 256
#define BATCH 128
#define HID   1024
#define NCLS  1000

static __device__ __forceinline__ float sigm(float x){ return 1.0f/(1.0f+__expf(-x)); }
static __device__ __forceinline__ float tanhx(float x){ return 2.0f/(1.0f+__expf(-2.0f*x)) - 1.0f; }
static __device__ __forceinline__ short bf16b(float x){
  __hip_bfloat16 h = __float2bfloat16(x);
  return __builtin_bit_cast(short, h);
}
static __device__ __forceinline__ float bf2f(short s){
  return __bfloat162float(__builtin_bit_cast(__hip_bfloat16, s));
}

// ---- prep: cast x [B][S][I] fp32 -> xbf [(s*128+b)][I] bf16 (permuted) ----
__global__ void cast_x_kernel(const float* __restrict__ x, short* __restrict__ xbf){
  int r = blockIdx.x;            // r = s*128 + b
  int s = r >> 7, b = r & 127;
  const float* src = x + ((size_t)b*SQLEN + s)*HID;
  short* dst = xbf + (size_t)r*HID;
  int k = threadIdx.x*4;
  float4 v = *(const float4*)(src + k);
  short4 o; o.x=bf16b(v.x); o.y=bf16b(v.y); o.z=bf16b(v.z); o.w=bf16b(v.w);
  *(short4*)(dst + k) = o;
}

__global__ void cast_w_kernel(const float* __restrict__ src, short* __restrict__ dst){
  int i = (blockIdx.x*256 + threadIdx.x)*4;
  float4 v = *(const float4*)(src + i);
  short4 o; o.x=bf16b(v.x); o.y=bf16b(v.y); o.z=bf16b(v.z); o.w=bf16b(v.w);
  *(short4*)(dst + i) = o;
}

__global__ void bias_kernel(const float* __restrict__ a, const float* __restrict__ b,
                            float* __restrict__ o){
  int i = blockIdx.x*256 + threadIdx.x;
  o[i] = a[i] + b[i];
}

// ---- fused xw-GEMM + persistent LSTM recurrence, v2 (chunk OFF-chain) ----
// Recurrence = byte-exact R1 structure (962us lstm). R6 regressed (2399us)
// because the gemm chunk sat between the h-store and the flag release --
// ON the inter-block critical chain. v2 places a SMALLER chunk (2 K-steps,
// ~0.8us) at the TOP of the step, after the previous release and before the
// flag spin: in steady state this consumes spin slack (~1.7us) and is
// off-chain. Tile schedule shifted one round early: rounds 0,1 in prologue;
// round k>=2 during steps 16(k-2)..16(k-2)+15, completing at step 16k-17,
// 16 steps before s=16k is first consumed (R6 was off by a round; the
// gating poll hid it). Gating polls retained: schedule violations degrade
// to spins, never wrong results. Deadlock-free: h-flag graph acyclic in t;
// gcnt deps are >=16 steps behind the least-advanced block (bounded drift).
// LDS 48KB, 2 blocks/CU preserved.
__global__ __launch_bounds__(256,2) void lstm_fused_kernel(
    const short* __restrict__ xbf, const short* __restrict__ wxh,
    const float* __restrict__ bias, const short* __restrict__ whh,
    short* __restrict__ xw, short* __restrict__ h_all,
    u32* __restrict__ flags, u32* __restrict__ gcnt)
{
  __shared__ f32x4 part[2][4][4][64];            // 32 KB reduce buffer
  __shared__ __align__(16) short As[4096];       // 8 KB gemm A stage [128][32]
  __shared__ __align__(16) short Bs[4096];       // 8 KB gemm B stage

  const int tid  = threadIdx.x;
  const int lane = tid & 63;
  const int wave = tid >> 6;            // recurrence K-slice 0..3 (256 each)
  const int l15  = lane & 15;
  const int quad = lane >> 4;
  const int bg = blockIdx.x & 7;        // batch group
  const int jg = blockIdx.x >> 3;       // 0..63
  const int b0 = bg*16;
  const int j0 = jg*16;
  const int ks0 = wave*256;
  const int wm = (wave>>1)*64, wn = (wave&1)*64; // gemm output quadrant
  const int c0 = wave*64 + lane;        // gemm staging slot, rep 0
  const int c1 = c0 + 256;              // rep 1

  __builtin_amdgcn_fence(__ATOMIC_ACQUIRE, "agent");  // once: clear stale L2

  f32x4 gacc[4][4];
  auto gzero = [&]{
    #pragma unroll
    for (int m=0;m<4;++m)
      #pragma unroll
      for (int n=0;n<4;++n) gacc[m][n] = (f32x4)0.0f;
  };
  // one gemm K-step (BK=32) of the current tile
  auto gemm_kk = [&](size_t gr0, size_t gn0, int kk){
    const int k0 = kk*32;
    __syncthreads();   // previous kk's LDS reads done
    __builtin_amdgcn_global_load_lds(
        (const void*)(xbf + (gr0 + (c0>>2))*HID + k0 + (c0&3)*8),
        (void*)((char*)As + wave*1024), 16, 0, 0);
    __builtin_amdgcn_global_load_lds(
        (const void*)(xbf + (gr0 + (c1>>2))*HID + k0 + (c1&3)*8),
        (void*)((char*)As + 4096 + wave*1024), 16, 0, 0);
    __builtin_amdgcn_global_load_lds(
        (const void*)(wxh + (gn0 + (c0>>2))*HID + k0 + (c0&3)*8),
        (void*)((char*)Bs + wave*1024), 16, 0, 0);
    __builtin_amdgcn_global_load_lds(
        (const void*)(wxh + (gn0 + (c1>>2))*HID + k0 + (c1&3)*8),
        (void*)((char*)Bs + 4096 + wave*1024), 16, 0, 0);
    __syncthreads();   // DMA landed (barrier drains vmcnt)
    short8 af[4], bv[4];
    #pragma unroll
    for (int m=0;m<4;++m) af[m] = *(const short8*)(As + (wm + m*16 + l15)*32 + quad*8);
    #pragma unroll
    for (int n=0;n<4;++n) bv[n] = *(const short8*)(Bs + (wn + n*16 + l15)*32 + quad*8);
    #pragma unroll
    for (int m=0;m<4;++m)
      #pragma unroll
      for (int n=0;n<4;++n)
        gacc[m][n] = __builtin_amdgcn_mfma_f32_16x16x32_bf16(af[m], bv[n], gacc[m][n], 0,0,0);
  };
  // tile epilogue: bias + pack -> agent-scope 8B stores, then count
  auto gemm_epi = [&](int gbm, int gbn){
    #pragma unroll
    for (int n=0;n<4;++n){
      int s = gbn*128 + wn + n*16;
      float bs = bias[s + l15];
      int g = s >> 10, jgi = (s & 1023) >> 4;
      #pragma unroll
      for (int m=0;m<4;++m){
        #pragma unroll
        for (int rg=0; rg<4; ++rg){
          u32 w0 = (u32)(unsigned short)bf16b(gacc[m][n][rg] + bs);
          u32 w1 = __shfl_down(w0, 1);
          u32 w2 = __shfl_down(w0, 2);
          u32 w3 = __shfl_down(w0, 3);
          if ((l15 & 3) == 0){
            u64 pk = (u64)w0 | ((u64)w1<<16) | ((u64)w2<<32) | ((u64)w3<<48);
            int rowin = wm + m*16 + quad*4 + rg;   // batch b 0..127
            __hip_atomic_store(
              (u64*)(xw + (((size_t)gbm*64 + jgi)*128 + rowin)*64 + g*16 + l15),
              pk, __ATOMIC_RELAXED, __HIP_MEMORY_SCOPE_AGENT);
          }
        }
      }
    }
    __syncthreads();   // all waves' xw stores drained (vmcnt0 at barrier)
    if (tid == 0)
      __hip_atomic_fetch_add(gcnt + gbm, 1u, __ATOMIC_RELAXED,
                             __HIP_MEMORY_SCOPE_AGENT);
  };

  // ---- gemm prologue: rounds 0 and 1 (chip-wide covers s=0..31) ----
  const int gbn = (int)blockIdx.x & 31;
  const size_t gn0 = (size_t)gbn*128;
  #pragma unroll 1
  for (int rr = 0; rr < 2; ++rr){
    gzero();
    const int gbm = rr*16 + ((int)blockIdx.x >> 5);
    const size_t gr0 = (size_t)gbm*128;
    for (int kk = 0; kk < 32; ++kk) gemm_kk(gr0, gn0, kk);
    gemm_epi(gbm, gbn);
  }
  gzero();

  // Whh slice, MFMA B-fragment layout (no pinning -- see rounds 2/3)
  short8 Bf[4][8];
  #pragma unroll
  for (int g=0; g<4; ++g)
    #pragma unroll
    for (int kit=0; kit<8; ++kit)
      Bf[g][kit] = *(const short8*)(whh + (size_t)(g*1024 + j0 + l15)*HID
                                    + ks0 + kit*32 + quad*8);

  u32* fgrp = flags + bg*64;            // one h-flag per producer block

  // elementwise cell mapping: cell = tid (r 0..15 x jj 0..15)
  const int r  = tid >> 4;
  const int jj = tid & 15;
  const int ln = (r>>2)*16 + jj;        // frag lane of cell
  const int rg = r & 3;                 // frag reg of cell
  float cc = 0.0f;                      // cell state in register

  // gated prefetch of xw for t=0
  short xwc[4];
  {
    while (__hip_atomic_load(gcnt + 0, __ATOMIC_RELAXED,
                             __HIP_MEMORY_SCOPE_AGENT) < 32u)
      __builtin_amdgcn_s_sleep(1);
    asm volatile("" ::: "memory");
    const short* xb = xw + (((size_t)0*64 + jg)*128 + b0 + r)*64 + jj;
    #pragma unroll
    for (int g=0; g<4; ++g) xwc[g] = xb[g*16];
  }

  for (int t = 0; t < SQLEN; ++t){
    const short* hin  = h_all + (size_t)t*131072;
    short*       hout = h_all + (size_t)(t+1)*131072;

    // gemm chunk: 2 K-steps of round k=2+(t>>4), placed AFTER the previous
    // release and BEFORE this step's spin -> consumes spin slack, off the
    // inter-block critical chain. Round k completes at step 16k-17, 16
    // steps before s=16k is first consumed.
    if (t < 224){
      const int k = 2 + (t>>4);
      const int gbm = k*16 + ((int)blockIdx.x >> 5);
      const size_t gr0 = (size_t)gbm*128;
      const int kkb = (t&15)*2;
      gemm_kk(gr0, gn0, kkb);
      gemm_kk(gr0, gn0, kkb+1);
      if ((t&15)==15){ gemm_epi(gbm, gbn); gzero(); }
    }

    // gated early prefetch of next step's xw (one satisfied poll + load;
    // by schedule s=t+1 was produced >=16 steps ago)
    short xwn[4];
    if (t < SQLEN-1){
      while (__hip_atomic_load(gcnt + (t+1), __ATOMIC_RELAXED,
                               __HIP_MEMORY_SCOPE_AGENT) < 32u)
        __builtin_amdgcn_s_sleep(1);
      asm volatile("" ::: "memory");
      const short* xb = xw + (((size_t)(t+1)*64 + jg)*128 + b0 + r)*64 + jj;
      #pragma unroll
      for (int g=0; g<4; ++g) xwn[g] = xb[g*16];
    }

    // per-wave spin: the 16 producer blocks of THIS wave's K-slice
    if (t){
      u32* fp = fgrp + wave*16 + l15;
      while (__hip_atomic_load(fp, __ATOMIC_RELAXED,
                               __HIP_MEMORY_SCOPE_AGENT) < (u32)t)
        __builtin_amdgcn_s_sleep(1);
      asm volatile("" ::: "memory");    // no hoist of h loads above the spin
    }

    // h fragments: plain cached coalesced 16B loads (fresh addresses)
    short8 Af[8];
    #pragma unroll
    for (int kit=0; kit<8; ++kit)
      Af[kit] = *(const short8*)(hin + (size_t)(b0 + l15)*HID
                                 + ks0 + kit*32 + quad*8);

    f32x4 acc[4];
    #pragma unroll
    for (int g=0; g<4; ++g) acc[g] = (f32x4)0.0f;
    #pragma unroll
    for (int kit=0; kit<8; ++kit)
      #pragma unroll
      for (int g=0; g<4; ++g)
        acc[g] = __builtin_amdgcn_mfma_f32_16x16x32_bf16(Af[kit], Bf[g][kit], acc[g],0,0,0);

    // single-pass cross-wave reduce, all 4 gates, double-buffered
    const int pb = t & 1;
    #pragma unroll
    for (int g=0; g<4; ++g) part[pb][wave][g][lane] = acc[g];
    __syncthreads();

    float gv[4];
    #pragma unroll
    for (int g=0; g<4; ++g){
      float s = bf2f(xwc[g]);
      #pragma unroll
      for (int w=0; w<4; ++w)
        s += ((const float*)&part[pb][w][g][ln])[rg];
      gv[g] = s;
    }

    float it = sigm(gv[0]), ft = sigm(gv[1]), ch = tanhx(gv[2]), ot = sigm(gv[3]);
    cc = cc*ft + it*ch;
    float hv = ot * tanhx(cc);

    // pack 4 adjacent cells -> one 8B write-through store
    u32 w0 = (u32)(unsigned short)bf16b(hv);
    u32 w1 = __shfl_down(w0, 1);
    u32 w2 = __shfl_down(w0, 2);
    u32 w3 = __shfl_down(w0, 3);
    if (!(tid & 3)){
      u64 hp = (u64)w0 | ((u64)w1<<16) | ((u64)w2<<32) | ((u64)w3<<48);
      __hip_atomic_store((u64*)(hout + (size_t)(b0 + r)*HID + j0 + jj), hp,
                         __ATOMIC_RELAXED, __HIP_MEMORY_SCOPE_AGENT);
    }
    xwc[0]=xwn[0]; xwc[1]=xwn[1]; xwc[2]=xwn[2]; xwc[3]=xwn[3];
    __syncthreads();   // all waves' h stores drained (vmcnt0 at barrier)

    if (t < SQLEN-1 && tid == 0)
      __hip_atomic_store(fgrp + jg, (u32)(t+1), __ATOMIC_RELAXED,
                         __HIP_MEMORY_SCOPE_AGENT);   // plain store, no RMW
  }
}

// ---- phase 3: out[b][c] = h[b]. Wfc[c] + bfc[c], fp32. 256 blocks:
// 32 b-groups x 8 class-slices of 125 (was 32 blocks -> 1/8 of CUs). ----
__global__ __launch_bounds__(256) void fc_kernel(const short* __restrict__ h,
    const float* __restrict__ wfc, const float* __restrict__ bfc, float* __restrict__ out)
{
  __shared__ float hs[4][1024];
  int tid = threadIdx.x;
  int b0 = (blockIdx.x >> 3)*4;
  int cs = (blockIdx.x & 7)*125;
  for (int i = tid; i < 4096; i += 256){
    int bb = i >> 10, k = i & 1023;
    hs[bb][k] = bf2f(h[(size_t)(b0+bb)*HID + k]);
  }
  __syncthreads();
  for (int c = cs + tid; c < cs + 125; c += 256){
    const float* w = wfc + (size_t)c*HID;
    float a0=0.f,a1=0.f,a2=0.f,a3=0.f;
    for (int k=0; k<1024; k+=4){
      float4 wv = *(const float4*)(w + k);
      a0 += wv.x*hs[0][k] + wv.y*hs[0][k+1] + wv.z*hs[0][k+2] + wv.w*hs[0][k+3];
      a1 += wv.x*hs[1][k] + wv.y*hs[1][k+1] + wv.z*hs[1][k+2] + wv.w*hs[1][k+3];
      a2 += wv.x*hs[2][k] + wv.y*hs[2][k+1] + wv.z*hs[2][k+2] + wv.w*hs[2][k+3];
      a3 += wv.x*hs[3][k] + wv.y*hs[3][k+1] + wv.z*hs[3][k+2] + wv.w*hs[3][k+3];
    }
    float bb = bfc[c];
    out[(size_t)(b0+0)*NCLS + c] = a0 + bb;
    out[(size_t)(b0+1)*NCLS + c] = a1 + bb;
    out[(size_t)(b0+2)*NCLS + c] = a2 + bb;
    out[(size_t)(b0+3)*NCLS + c] = a3 + bb;
  }
}

extern "C" void kernel_launch(void* const* d_in, const int* in_sizes, int n_in,
                              void* d_out, int out_size, void* d_ws, size_t ws_size,
                              hipStream_t stream) {
  const float* x   = (const float*)d_in[0];
  const float* Wxh = (const float*)d_in[1];
  const float* bxh = (const float*)d_in[2];
  const float* Whh = (const float*)d_in[3];
  const float* bhh = (const float*)d_in[4];
  const float* Wfc = (const float*)d_in[5];
  const float* bfc = (const float*)d_in[6];
  float* out = (float*)d_out;

  char* ws = (char*)d_ws;
  // xbf stays LIVE through the fused kernel (gemm A source) -> h_all does
  // not alias it; workspace high-water ~422 MB.
  short*    xbf   = (short*)(ws + 0);            // 64 MB
  short*    wxhb  = (short*)(ws + 68157440);     // 65 MB
  short*    whhb  = (short*)(ws + 76546048);     // 73 MB
  float*    biasg = (float*)(ws + 84934656);     // 81 MB
  short*    xw    = (short*)(ws + 85983232);     // 82 MB, 256 MB gate-blocked
  short*    h_all = (short*)(ws + 354418688);    // 338 MB, 257 x 256 KB
  u32*      flags = (u32*)(ws + 421789696);      // 512 h-flags
  u32*      gcnt  = (u32*)(ws + 421793792);      // 256 per-s gemm counters

  hipMemsetAsync(flags, 0, 8192, stream);        // covers flags + gcnt

  cast_x_kernel<<<32768, 256, 0, stream>>>(x, xbf);
  cast_w_kernel<<<4096, 256, 0, stream>>>(Wxh, wxhb);
  cast_w_kernel<<<4096, 256, 0, stream>>>(Whh, whhb);
  bias_kernel  <<<16,   256, 0, stream>>>(bxh, bhh, biasg);
  hipMemsetAsync(h_all, 0, 262144, stream);      // h_all[0] = 0
  lstm_fused_kernel<<<512, 256, 0, stream>>>(xbf, wxhb, biasg, whhb,
                                             xw, h_all, flags, gcnt);
  fc_kernel    <<<256,  256, 0, stream>>>(h_all + (size_t)SQLEN*131072, Wfc, bfc, out);
}